// Round 7
// baseline (1681.945 us; speedup 1.0000x reference)
//
#include <hip/hip_runtime.h>

#define C 128
#define MAXNB 1024
typedef unsigned int uint;
typedef unsigned short ushort;
typedef __attribute__((ext_vector_type(4))) float f32x4;
typedef __attribute__((ext_vector_type(8))) short bf16x8;

__device__ __forceinline__ float blo(uint u) { return __uint_as_float(u << 16); }
__device__ __forceinline__ float bhi(uint u) { return __uint_as_float(u & 0xFFFF0000u); }

// ---------------- A1: per-block bucket histogram (no atomics to global) ----------------
__global__ __launch_bounds__(256) void k_hist(const int* __restrict__ col,
                                              int* __restrict__ counts,
                                              int nE, int NB, int NBLK) {
    __shared__ int hist[MAXNB];
    const int t = threadIdx.x, blk = blockIdx.x;
    for (int i = t; i < NB; i += 256) hist[i] = 0;
    __syncthreads();
    const int base = blk * 2048;
    for (int k = 0; k < 8; ++k) {
        int e = base + k * 256 + t;
        if (e < nE) atomicAdd(&hist[col[e] >> 7], 1);
    }
    __syncthreads();
    for (int i = t; i < NB; i += 256) counts[i * NBLK + blk] = hist[i];
}

// ---------------- scan of counts[scanN] (exclusive), 3 kernels ----------------
__global__ __launch_bounds__(256) void k_scan1(int* __restrict__ counts,
                                               int* __restrict__ bsum, int scanN) {
    __shared__ int s[256];
    int t = threadIdx.x;
    int i = blockIdx.x * 256 + t;
    int v = (i < scanN) ? counts[i] : 0;
    s[t] = v;
    __syncthreads();
    for (int d = 1; d < 256; d <<= 1) {
        int a = (t >= d) ? s[t - d] : 0;
        __syncthreads();
        s[t] += a;
        __syncthreads();
    }
    if (i < scanN) counts[i] = s[t] - v;
    if (t == 255) bsum[blockIdx.x] = s[255];
}

__global__ __launch_bounds__(256) void k_scan2(int* __restrict__ bsum, int nb) {
    __shared__ int s[256];
    __shared__ int carry;
    int t = threadIdx.x;
    if (t == 0) carry = 0;
    __syncthreads();
    int nch = (nb + 255) / 256;
    for (int c = 0; c < nch; ++c) {
        int i = c * 256 + t;
        int v = (i < nb) ? bsum[i] : 0;
        s[t] = v;
        __syncthreads();
        for (int d = 1; d < 256; d <<= 1) {
            int a = (t >= d) ? s[t - d] : 0;
            __syncthreads();
            s[t] += a;
            __syncthreads();
        }
        int cb = carry;
        if (i < nb) bsum[i] = s[t] - v + cb;
        int tot = s[255];
        __syncthreads();
        if (t == 0) carry = cb + tot;
        __syncthreads();
    }
}

__global__ __launch_bounds__(256) void k_scan3(int* __restrict__ counts,
                                               const int* __restrict__ bsum,
                                               int* __restrict__ bstart,
                                               int scanN, int NBLK, int NB, int nE) {
    int i = blockIdx.x * 256 + threadIdx.x;
    if (i >= scanN) return;
    int v = counts[i] + bsum[i >> 8];
    counts[i] = v;
    if (i % NBLK == 0) {
        bstart[i / NBLK] = v;
        if (i == 0) bstart[NB] = nE;
    }
}

// ---------------- A2: scatter edges into bucket regions (no global atomics) ----------------
__global__ __launch_bounds__(256) void k_scatter(const int* __restrict__ ei,
                                                 const float* __restrict__ ew,
                                                 const int* __restrict__ counts,
                                                 int2* __restrict__ ev2,
                                                 int nE, int NB, int NBLK) {
    __shared__ int base_l[MAXNB];
    __shared__ int cnt_l[MAXNB];
    const int t = threadIdx.x, blk = blockIdx.x;
    for (int i = t; i < NB; i += 256) {
        base_l[i] = counts[i * NBLK + blk];
        cnt_l[i] = 0;
    }
    __syncthreads();
    const int base = blk * 2048;
    for (int k = 0; k < 8; ++k) {
        int e = base + k * 256 + t;
        if (e >= nE) continue;
        int c = ei[nE + e];
        int row = ei[e];
        int b = c >> 7;
        int pos = base_l[b] + atomicAdd(&cnt_l[b], 1);
        ev2[pos] = make_int2(((c & 127) << 25) | row, __float_as_int(ew[e]));
    }
}

// ---------------- B1: per-bucket degree -> dis (LDS f32 adds) ----------------
__global__ __launch_bounds__(256) void k_deg(const int2* __restrict__ ev2,
                                             const int* __restrict__ bstart,
                                             float* __restrict__ dis, int n) {
    __shared__ float wsum[128];
    const int t = threadIdx.x, b = blockIdx.x;
    if (t < 128) wsum[t] = 0.f;
    __syncthreads();
    const int start = bstart[b], end = bstart[b + 1];
    for (int e = start + t; e < end; e += 256) {
        int2 E = ev2[e];
        atomicAdd(&wsum[(uint)E.x >> 25], __int_as_float(E.y));
    }
    __syncthreads();
    int col = (b << 7) + t;
    if (t < 128 && col < n) dis[col] = rsqrtf(1.0f + wsum[t]);
}

// ---------------- xb' = bf16(dis[r] * x[r]) ----------------
__global__ __launch_bounds__(256) void k_cvt(const float4* __restrict__ x4,
                                             const float* __restrict__ dis,
                                             ushort4* __restrict__ xb4, long total4) {
    long i = (long)blockIdx.x * 256 + threadIdx.x;
    if (i >= total4) return;
    float d = dis[i >> 5];
    float4 v = x4[i];
    ushort4 r;
#define RNE(OUT, F)                                                     \
    {                                                                   \
        uint u = __float_as_uint((F) * d);                              \
        OUT = (ushort)((u + 0x7FFFu + ((u >> 16) & 1u)) >> 16);         \
    }
    RNE(r.x, v.x) RNE(r.y, v.y) RNE(r.z, v.z) RNE(r.w, v.w)
#undef RNE
    xb4[i] = r;
}

// ---------------- WbT[o][k] = bf16(W[k][o]) ----------------
__global__ __launch_bounds__(256) void k_wcvt(const float* __restrict__ W,
                                              ushort* __restrict__ WbT) {
    int idx = blockIdx.x * 256 + threadIdx.x;   // 16384 total
    int k = idx >> 7, o = idx & 127;
    uint u = __float_as_uint(W[idx]);
    WbT[o * 128 + k] = (ushort)((u + 0x7FFFu + ((u >> 16) & 1u)) >> 16);
}

// ---------------- B2: bucket aggregation with 64KB LDS accumulator ----------------
// acc[col_local][ch] init = xb[col] (self-loop); edges add w * xb[row]; out = dis_c * acc.
__global__ __launch_bounds__(256) void k_agg(const ushort* __restrict__ xb,
                                             const int2* __restrict__ ev2,
                                             const int* __restrict__ bstart,
                                             const float* __restrict__ dis,
                                             float* __restrict__ out, int n) {
    __shared__ float acc_s[128 * 128];   // 64 KB
    __shared__ float dis_l[128];
    const int t = threadIdx.x, b = blockIdx.x;
    const int col0 = b << 7;
    if (t < 128) dis_l[t] = (col0 + t < n) ? dis[col0 + t] : 0.f;

    const uint4* xb4 = (const uint4*)xb;   // 16 uint4 per row
    for (int s = t; s < 2048; s += 256) {
        int r = s >> 4, q = s & 15;
        int col = col0 + r;
        float4 lo = make_float4(0.f, 0.f, 0.f, 0.f), hi = lo;
        if (col < n) {
            uint4 g = xb4[(size_t)col * 16 + q];
            lo = make_float4(blo(g.x), bhi(g.x), blo(g.y), bhi(g.y));
            hi = make_float4(blo(g.z), bhi(g.z), blo(g.w), bhi(g.w));
        }
        *(float4*)&acc_s[r * 128 + q * 8] = lo;
        *(float4*)&acc_s[r * 128 + q * 8 + 4] = hi;
    }
    __syncthreads();

    const int sub = t >> 4, lane16 = t & 15;
    const int start = bstart[b], end = bstart[b + 1];

#define ADDS(E, G)                                                        \
    {                                                                     \
        float w = __int_as_float(E.y);                                    \
        float* ap = &acc_s[((uint)E.x >> 25) * 128 + lane16 * 8];         \
        atomicAdd(ap + 0, w * blo(G.x));                                  \
        atomicAdd(ap + 1, w * bhi(G.x));                                  \
        atomicAdd(ap + 2, w * blo(G.y));                                  \
        atomicAdd(ap + 3, w * bhi(G.y));                                  \
        atomicAdd(ap + 4, w * blo(G.z));                                  \
        atomicAdd(ap + 5, w * bhi(G.z));                                  \
        atomicAdd(ap + 6, w * blo(G.w));                                  \
        atomicAdd(ap + 7, w * bhi(G.w));                                  \
    }

    for (int e = start + sub; e < end; e += 32) {
        int2 E0 = ev2[e];
        bool h2 = (e + 16) < end;
        int2 E1 = h2 ? ev2[e + 16] : make_int2(0, 0);
        uint4 g0 = xb4[(size_t)(E0.x & 0x1FFFFFF) * 16 + lane16];
        uint4 g1 = h2 ? xb4[(size_t)(E1.x & 0x1FFFFFF) * 16 + lane16]
                      : make_uint4(0, 0, 0, 0);
        ADDS(E0, g0)
        if (h2) ADDS(E1, g1)
    }
#undef ADDS
    __syncthreads();

    float4* out4 = (float4*)out;
    for (int s = t; s < 4096; s += 256) {
        int r = s >> 5, q = s & 31;
        int col = col0 + r;
        if (col >= n) continue;
        float dv = dis_l[r];
        float4 a = *(float4*)&acc_s[r * 128 + q * 4];
        out4[(size_t)col * 32 + q] = make_float4(dv * a.x, dv * a.y, dv * a.z, dv * a.w);
    }
}

// ---------------- MFMA GEMM (swapped operands) + fused BN block partials ----------------
__global__ __launch_bounds__(256, 4) void k_gemm(float* __restrict__ io,
                                                 const ushort* __restrict__ WbT,
                                                 float* __restrict__ part, int n) {
    __shared__ float ls[256];
    const int t = threadIdx.x;
    ls[t] = 0.f;
    __syncthreads();

    const int lane = t & 63;
    const int wv = t >> 6;
    const int lr = lane & 15;
    const int lk = lane >> 4;
    const long m = (long)blockIdx.x * 64 + wv * 16 + lr;
    const bool inr = m < (long)n;

    bf16x8 bfr[4];
#pragma unroll
    for (int s = 0; s < 4; ++s) {
        uint4 q0 = make_uint4(0, 0, 0, 0), q1 = q0;
        if (inr) {
            const uint4* p = (const uint4*)(io + (size_t)m * C + s * 32 + lk * 8);
            q0 = p[0];
            q1 = p[1];
        }
        union { uint u[4]; bf16x8 v; } cv;
        cv.u[0] = __builtin_amdgcn_perm(q0.y + 0x8000u, q0.x + 0x8000u, 0x07060302u);
        cv.u[1] = __builtin_amdgcn_perm(q0.w + 0x8000u, q0.z + 0x8000u, 0x07060302u);
        cv.u[2] = __builtin_amdgcn_perm(q1.y + 0x8000u, q1.x + 0x8000u, 0x07060302u);
        cv.u[3] = __builtin_amdgcn_perm(q1.w + 0x8000u, q1.z + 0x8000u, 0x07060302u);
        bfr[s] = cv.v;
    }

    f32x4 acc[8];
#pragma unroll
    for (int ot = 0; ot < 8; ++ot) acc[ot] = (f32x4){0.f, 0.f, 0.f, 0.f};

#pragma unroll 2
    for (int ot = 0; ot < 8; ++ot) {
        const ushort* wp = WbT + (ot * 16 + lr) * 128 + lk * 8;
        bf16x8 a0 = *(const bf16x8*)(wp);
        bf16x8 a1 = *(const bf16x8*)(wp + 32);
        bf16x8 a2 = *(const bf16x8*)(wp + 64);
        bf16x8 a3 = *(const bf16x8*)(wp + 96);
        acc[ot] = __builtin_amdgcn_mfma_f32_16x16x32_bf16(a0, bfr[0], acc[ot], 0, 0, 0);
        acc[ot] = __builtin_amdgcn_mfma_f32_16x16x32_bf16(a1, bfr[1], acc[ot], 0, 0, 0);
        acc[ot] = __builtin_amdgcn_mfma_f32_16x16x32_bf16(a2, bfr[2], acc[ot], 0, 0, 0);
        acc[ot] = __builtin_amdgcn_mfma_f32_16x16x32_bf16(a3, bfr[3], acc[ot], 0, 0, 0);
    }

    if (inr) {
        float* orow = io + (size_t)m * C + lk * 4;
#pragma unroll
        for (int ot = 0; ot < 8; ++ot)
            *(float4*)(orow + ot * 16) =
                make_float4(acc[ot][0], acc[ot][1], acc[ot][2], acc[ot][3]);
        // BN partials: channel = ot*16 + lk*4 + j
#pragma unroll
        for (int ot = 0; ot < 8; ++ot) {
#pragma unroll
            for (int j = 0; j < 4; ++j) {
                float v = acc[ot][j];
                int ch = ot * 16 + lk * 4 + j;
                atomicAdd(&ls[ch], v);
                atomicAdd(&ls[128 + ch], v * v);
            }
        }
    }
    __syncthreads();
    part[(size_t)blockIdx.x * 256 + t] = ls[t];
}

__global__ __launch_bounds__(256) void k_finish(const float* __restrict__ part,
                                                float* __restrict__ sums, int nblk) {
    int t = threadIdx.x;
    float s = 0.f;
    for (int b = blockIdx.x; b < nblk; b += gridDim.x) s += part[(size_t)b * 256 + t];
    atomicAdd(&sums[t], s);
}

// ---------------- BN apply + ReLU (in place) ----------------
__global__ __launch_bounds__(256) void k_apply(float* __restrict__ out,
                                               const float* __restrict__ sums,
                                               const float* __restrict__ gamma,
                                               const float* __restrict__ beta,
                                               int n) {
    size_t idx = (size_t)blockIdx.x * 256 + threadIdx.x;
    size_t total = (size_t)n * 32;
    if (idx >= total) return;
    int cg = (int)(idx & 31);
    int c0 = cg * 4;
    float inv_n = 1.0f / (float)n;
    float4 v = ((const float4*)out)[idx];
    float4 r;
#define BN1(OUT, VIN, J)                                                   \
    {                                                                      \
        float mean = sums[c0 + J] * inv_n;                                 \
        float var  = fmaxf(sums[C + c0 + J] * inv_n - mean * mean, 0.f);   \
        float sc   = rsqrtf(var + 1e-5f) * gamma[c0 + J];                  \
        OUT = fmaxf(fmaf(VIN - mean, sc, beta[c0 + J]), 0.f);              \
    }
    BN1(r.x, v.x, 0)
    BN1(r.y, v.y, 1)
    BN1(r.z, v.z, 2)
    BN1(r.w, v.w, 3)
#undef BN1
    ((float4*)out)[idx] = r;
}

extern "C" void kernel_launch(void* const* d_in, const int* in_sizes, int n_in,
                              void* d_out, int out_size, void* d_ws, size_t ws_size,
                              hipStream_t stream) {
    const float* x     = (const float*)d_in[0];
    const int*   ei    = (const int*)d_in[1];   // [2, E]: row = ei[e], col = ei[E+e]
    const float* ew    = (const float*)d_in[2];
    const float* W     = (const float*)d_in[3];
    const float* gamma = (const float*)d_in[4];
    const float* beta  = (const float*)d_in[5];

    const int n  = in_sizes[0] / C;
    const int nE = in_sizes[2];

    const int NB     = (n + 127) >> 7;            // 128-col buckets
    const int NBLK   = (nE + 2047) / 2048;        // A1/A2 blocks
    const int scanN  = NB * NBLK;
    const int scanB  = (scanN + 255) / 256;
    const int gB     = (n + 63) / 64;             // gemm blocks

    float* out = (float*)d_out;
    char* p = (char*)d_ws;
#define ALLOC(TYPE, NAME, BYTES) \
    TYPE NAME = (TYPE)p; p += ((size_t)(BYTES) + 255) & ~(size_t)255;
    ALLOC(int2*,   ev2,    (size_t)nE * 8)
    ALLOC(ushort*, xb,     (size_t)n * C * 2)
    ALLOC(int*,    counts, (size_t)scanN * 4)
    ALLOC(int*,    bsum,   (size_t)scanB * 4)
    ALLOC(int*,    bstart, (size_t)(NB + 1) * 4)
    ALLOC(float*,  dis,    (size_t)n * 4)
    ALLOC(ushort*, WbT,    32768)
    ALLOC(float*,  sums,   1024)
    ALLOC(float*,  part,   (size_t)gB * 1024)
#undef ALLOC

    const long total4 = (long)n * 32;  // n*C/4

    hipMemsetAsync(sums, 0, 256 * 4, stream);

    k_hist   <<<NBLK, 256, 0, stream>>>(ei + nE, counts, nE, NB, NBLK);
    k_scan1  <<<scanB, 256, 0, stream>>>(counts, bsum, scanN);
    k_scan2  <<<1, 256, 0, stream>>>(bsum, scanB);
    k_scan3  <<<scanB, 256, 0, stream>>>(counts, bsum, bstart, scanN, NBLK, NB, nE);
    k_scatter<<<NBLK, 256, 0, stream>>>(ei, ew, counts, ev2, nE, NB, NBLK);
    k_deg    <<<NB, 256, 0, stream>>>(ev2, bstart, dis, n);
    k_wcvt   <<<64, 256, 0, stream>>>(W, WbT);
    k_cvt    <<<(int)((total4 + 255) / 256), 256, 0, stream>>>((const float4*)x, dis, (ushort4*)xb, total4);
    k_agg    <<<NB, 256, 0, stream>>>(xb, ev2, bstart, dis, out, n);
    k_gemm   <<<gB, 256, 0, stream>>>(out, WbT, part, n);
    k_finish <<<16, 256, 0, stream>>>(part, sums, gB);
    k_apply  <<<(int)((total4 + 255) / 256), 256, 0, stream>>>(out, sums, gamma, beta, n);
}

// Round 8
// 276.184 us; speedup vs baseline: 6.0899x; 6.0899x over previous
//
#include <hip/hip_runtime.h>

#define C 128
typedef unsigned int uint;
typedef unsigned short ushort;
typedef unsigned long long u64;
typedef __attribute__((ext_vector_type(4))) float f32x4;
typedef __attribute__((ext_vector_type(8))) short bf16x8;

// ---------------- pass 1: packed degree histogram + ticket ----------------
// packed[c]: hi32 = edge count, lo32 = sum(w) in 2^22 fixed point.
// atomicAdd's return value doubles as the CSR ticket (position within segment).
// 8 edges per thread -> 8 independent atomics in flight (latency hiding).
__global__ __launch_bounds__(256) void k_deg_hist(const int* __restrict__ col,
                                                  const float* __restrict__ ew,
                                                  u64* __restrict__ packed,
                                                  ushort* __restrict__ tkt, int nE) {
    const int t = threadIdx.x;
    const int base = blockIdx.x * 2048 + t;
    u64 old[8];
#pragma unroll
    for (int k = 0; k < 8; ++k) {
        int e = base + k * 256;
        if (e < nE) {
            int c = col[e];
            u64 add = (1ull << 32) | (u64)(uint)__float2uint_rn(ew[e] * 4194304.0f);
            old[k] = atomicAdd(&packed[c], add);
        }
    }
#pragma unroll
    for (int k = 0; k < 8; ++k) {
        int e = base + k * 256;
        if (e < nE) tkt[e] = (ushort)(old[k] >> 32);
    }
}

// ---------------- scan1: dis = rsqrt(1 + wsum) fused; exclusive scan of counts ----------------
__global__ __launch_bounds__(256) void k_scan1(const u64* __restrict__ packed,
                                               float* __restrict__ dis,
                                               int* __restrict__ offs,
                                               int* __restrict__ bsum, int n) {
    __shared__ int s[256];
    int t = threadIdx.x;
    int i = blockIdx.x * 256 + t;
    int v = 0;
    if (i < n) {
        u64 p = packed[i];
        v = (int)(p >> 32);
        float deg = 1.0f + (float)(p & 0xFFFFFFFFull) * 2.384185791015625e-7f;
        dis[i] = rsqrtf(deg);
    }
    s[t] = v;
    __syncthreads();
    for (int d = 1; d < 256; d <<= 1) {
        int a = (t >= d) ? s[t - d] : 0;
        __syncthreads();
        s[t] += a;
        __syncthreads();
    }
    if (i < n) offs[i] = s[t] - v;
    if (t == 255) bsum[blockIdx.x] = s[255];
}

__global__ __launch_bounds__(512) void k_scan2(int* __restrict__ bsum, int nb) {
    __shared__ int s[512];
    int t = threadIdx.x;
    int v = (t < nb) ? bsum[t] : 0;
    s[t] = v;
    __syncthreads();
    for (int d = 1; d < 512; d <<= 1) {
        int a = (t >= d) ? s[t - d] : 0;
        __syncthreads();
        s[t] += a;
        __syncthreads();
    }
    if (t < nb) bsum[t] = s[t] - v;
}

__global__ __launch_bounds__(256) void k_scan3(int* __restrict__ offs,
                                               const int* __restrict__ bsum,
                                               int n, int nE) {
    int i = blockIdx.x * 256 + threadIdx.x;
    if (i < n) offs[i] += bsum[i >> 8];
    if (i == 0) offs[n] = nE;
}

// ---------------- xb' = bf16(dis[r] * x[r]) ----------------
__global__ __launch_bounds__(256) void k_cvt(const float4* __restrict__ x4,
                                             const float* __restrict__ dis,
                                             ushort4* __restrict__ xb4, long total4) {
    long i = (long)blockIdx.x * 256 + threadIdx.x;
    if (i >= total4) return;
    float d = dis[i >> 5];
    float4 v = x4[i];
    ushort4 r;
#define RNE(OUT, F)                                                     \
    {                                                                   \
        uint u = __float_as_uint((F) * d);                              \
        OUT = (ushort)((u + 0x7FFFu + ((u >> 16) & 1u)) >> 16);         \
    }
    RNE(r.x, v.x) RNE(r.y, v.y) RNE(r.z, v.z) RNE(r.w, v.w)
#undef RNE
    xb4[i] = r;
}

// ---------------- WbT[o][k] = bf16(W[k][o]) ----------------
__global__ __launch_bounds__(256) void k_wcvt(const float* __restrict__ W,
                                              ushort* __restrict__ WbT) {
    int idx = blockIdx.x * 256 + threadIdx.x;   // 16384 total
    int k = idx >> 7, o = idx & 127;
    uint u = __float_as_uint(W[idx]);
    WbT[o * 128 + k] = (ushort)((u + 0x7FFFu + ((u >> 16) & 1u)) >> 16);
}

// ---------------- bin edges into CSR (no atomics, no gathers) ----------------
__global__ __launch_bounds__(256) void k_build(const int* __restrict__ ei,
                                               const float* __restrict__ ew,
                                               const int* __restrict__ offs,
                                               const ushort* __restrict__ tkt,
                                               int2* __restrict__ ev, int nE) {
    int e = blockIdx.x * 256 + threadIdx.x;
    if (e >= nE) return;
    int row = ei[e];
    int c = ei[nE + e];
    int pos = offs[c] + tkt[e];
    ev[pos] = make_int2(row, __float_as_int(ew[e]));
}

// ---------------- segment aggregation ----------------
// out[col] = dis[col] * ( xb'[col] + sum_e w_e * xb'[row_e] )   (self-loop = weight-1 edge)
__device__ __forceinline__ float blo(uint u) { return __uint_as_float(u << 16); }
__device__ __forceinline__ float bhi(uint u) { return __uint_as_float(u & 0xFFFF0000u); }

__global__ __launch_bounds__(256) void k_segagg(const ushort* __restrict__ xb,
                                                const int2* __restrict__ ev,
                                                const int* __restrict__ offs,
                                                const float* __restrict__ dis,
                                                float* __restrict__ out, int n) {
    const int lane = threadIdx.x & 15;   // 0..15
    const int sub  = threadIdx.x >> 4;   // 0..15
    const int col  = blockIdx.x * 16 + sub;
    if (col >= n) return;

    uint4 sv = *(const uint4*)(xb + (size_t)col * C + lane * 8);
    float acc[8] = {blo(sv.x), bhi(sv.x), blo(sv.y), bhi(sv.y),
                    blo(sv.z), bhi(sv.z), blo(sv.w), bhi(sv.w)};

    int i = offs[col];
    const int end = offs[col + 1];

#define EDGE(E, V)                                                        \
    {                                                                     \
        float nw = __int_as_float(E.y);                                   \
        acc[0] = fmaf(nw, blo(V.x), acc[0]);                              \
        acc[1] = fmaf(nw, bhi(V.x), acc[1]);                              \
        acc[2] = fmaf(nw, blo(V.y), acc[2]);                              \
        acc[3] = fmaf(nw, bhi(V.y), acc[3]);                              \
        acc[4] = fmaf(nw, blo(V.z), acc[4]);                              \
        acc[5] = fmaf(nw, bhi(V.z), acc[5]);                              \
        acc[6] = fmaf(nw, blo(V.w), acc[6]);                              \
        acc[7] = fmaf(nw, bhi(V.w), acc[7]);                              \
    }

    for (; i + 2 <= end; i += 2) {
        int2 e0 = ev[i], e1 = ev[i + 1];
        uint4 v0 = *(const uint4*)(xb + (size_t)e0.x * C + lane * 8);
        uint4 v1 = *(const uint4*)(xb + (size_t)e1.x * C + lane * 8);
        EDGE(e0, v0)
        EDGE(e1, v1)
    }
    if (i < end) {
        int2 e0 = ev[i];
        uint4 v0 = *(const uint4*)(xb + (size_t)e0.x * C + lane * 8);
        EDGE(e0, v0)
    }
#undef EDGE

    float d = dis[col];
    float4* orow = (float4*)(out + (size_t)col * C) + lane * 2;
    orow[0] = make_float4(d * acc[0], d * acc[1], d * acc[2], d * acc[3]);
    orow[1] = make_float4(d * acc[4], d * acc[5], d * acc[6], d * acc[7]);
}

// ---------------- MFMA GEMM: io = io @ W (in place), swapped operands ----------------
// A = W^T tile (from WbT, 16B contiguous per lane), B = agg^T tile (f32->bf16 in reg).
// D comes out transposed: lane owns 4 consecutive channels of ONE row -> float4 stores.
// No LDS, no barriers, no atomics.
__global__ __launch_bounds__(256, 4) void k_gemm(float* __restrict__ io,
                                                 const ushort* __restrict__ WbT,
                                                 int n) {
    const int t = threadIdx.x;
    const int lane = t & 63;
    const int wv = t >> 6;          // wave 0..3
    const int lr = lane & 15;       // row within 16-row tile (D col)
    const int lk = lane >> 4;       // k-chunk 0..3 (and D row-group = channel group)
    const long m = (long)blockIdx.x * 64 + wv * 16 + lr;
    const bool inr = m < (long)n;

    // ---- B fragments: agg row m, 8 consecutive f32 -> bf16x8 (round-half-up) ----
    bf16x8 b[4];
#pragma unroll
    for (int s = 0; s < 4; ++s) {
        uint4 q0 = make_uint4(0, 0, 0, 0), q1 = q0;
        if (inr) {
            const uint4* p = (const uint4*)(io + (size_t)m * C + s * 32 + lk * 8);
            q0 = p[0];
            q1 = p[1];
        }
        union { uint u[4]; bf16x8 v; } cv;
        cv.u[0] = __builtin_amdgcn_perm(q0.y + 0x8000u, q0.x + 0x8000u, 0x07060302u);
        cv.u[1] = __builtin_amdgcn_perm(q0.w + 0x8000u, q0.z + 0x8000u, 0x07060302u);
        cv.u[2] = __builtin_amdgcn_perm(q1.y + 0x8000u, q1.x + 0x8000u, 0x07060302u);
        cv.u[3] = __builtin_amdgcn_perm(q1.w + 0x8000u, q1.z + 0x8000u, 0x07060302u);
        b[s] = cv.v;
    }

    // ---- MFMA over 8 channel-tiles (ot): acc[ot] = W^T(ot) x agg^T ----
    f32x4 acc[8];
#pragma unroll
    for (int ot = 0; ot < 8; ++ot) acc[ot] = (f32x4){0.f, 0.f, 0.f, 0.f};

#pragma unroll 2
    for (int ot = 0; ot < 8; ++ot) {
        const ushort* wp = WbT + (ot * 16 + lr) * 128 + lk * 8;
        bf16x8 a0 = *(const bf16x8*)(wp);
        bf16x8 a1 = *(const bf16x8*)(wp + 32);
        bf16x8 a2 = *(const bf16x8*)(wp + 64);
        bf16x8 a3 = *(const bf16x8*)(wp + 96);
        acc[ot] = __builtin_amdgcn_mfma_f32_16x16x32_bf16(a0, b[0], acc[ot], 0, 0, 0);
        acc[ot] = __builtin_amdgcn_mfma_f32_16x16x32_bf16(a1, b[1], acc[ot], 0, 0, 0);
        acc[ot] = __builtin_amdgcn_mfma_f32_16x16x32_bf16(a2, b[2], acc[ot], 0, 0, 0);
        acc[ot] = __builtin_amdgcn_mfma_f32_16x16x32_bf16(a3, b[3], acc[ot], 0, 0, 0);
    }

    // ---- store: lane's 4 consecutive channels of its row, per ot ----
    if (inr) {
        float* orow = io + (size_t)m * C + lk * 4;
#pragma unroll
        for (int ot = 0; ot < 8; ++ot)
            *(float4*)(orow + ot * 16) =
                make_float4(acc[ot][0], acc[ot][1], acc[ot][2], acc[ot][3]);
    }
}

// ---------------- BN stats: per-block partials (no global atomics) ----------------
__global__ __launch_bounds__(1024) void k_stats(const float4* __restrict__ o4,
                                                float* __restrict__ part, int n) {
    const int t = threadIdx.x;
    const int cg = t & 31;   // float4 column group
    const int rl = t >> 5;   // 0..31 row lanes
    float4 s = make_float4(0.f, 0.f, 0.f, 0.f);
    float4 q = s;
    for (int r = blockIdx.x * 32 + rl; r < n; r += gridDim.x * 32) {
        float4 v = o4[(size_t)r * 32 + cg];
        s.x += v.x; s.y += v.y; s.z += v.z; s.w += v.w;
        q.x = fmaf(v.x, v.x, q.x); q.y = fmaf(v.y, v.y, q.y);
        q.z = fmaf(v.z, v.z, q.z); q.w = fmaf(v.w, v.w, q.w);
    }
    __shared__ float4 ls[1024];
    __shared__ float4 lq[1024];
    ls[t] = s; lq[t] = q;
    __syncthreads();
    for (int d = 512; d >= 32; d >>= 1) {
        if (t < d) {
            float4 a = ls[t + d], bq = lq[t + d];
            ls[t].x += a.x; ls[t].y += a.y; ls[t].z += a.z; ls[t].w += a.w;
            lq[t].x += bq.x; lq[t].y += bq.y; lq[t].z += bq.z; lq[t].w += bq.w;
        }
        __syncthreads();
    }
    if (t < 32) {
        ((float4*)part)[blockIdx.x * 64 + t] = ls[t];        // s: channels t*4..t*4+3
        ((float4*)part)[blockIdx.x * 64 + 32 + t] = lq[t];   // q
    }
}

__global__ __launch_bounds__(256) void k_finish(const float* __restrict__ part,
                                                float* __restrict__ sums, int nblk) {
    int t = threadIdx.x;   // 0..127 -> sum channel t; 128..255 -> sumsq channel t-128
    float s = 0.f;
    for (int b = blockIdx.x; b < nblk; b += gridDim.x) s += part[b * 256 + t];
    atomicAdd(&sums[t], s);
}

// ---------------- BN apply + ReLU (in place) ----------------
__global__ __launch_bounds__(256) void k_apply(float* __restrict__ out,
                                               const float* __restrict__ sums,
                                               const float* __restrict__ gamma,
                                               const float* __restrict__ beta,
                                               int n) {
    size_t idx = (size_t)blockIdx.x * 256 + threadIdx.x;
    size_t total = (size_t)n * 32;
    if (idx >= total) return;
    int cg = (int)(idx & 31);
    int c0 = cg * 4;
    float inv_n = 1.0f / (float)n;
    float4 v = ((const float4*)out)[idx];
    float4 r;
#define BN1(OUT, VIN, J)                                                   \
    {                                                                      \
        float mean = sums[c0 + J] * inv_n;                                 \
        float var  = fmaxf(sums[C + c0 + J] * inv_n - mean * mean, 0.f);   \
        float sc   = rsqrtf(var + 1e-5f) * gamma[c0 + J];                  \
        OUT = fmaxf(fmaf(VIN - mean, sc, beta[c0 + J]), 0.f);              \
    }
    BN1(r.x, v.x, 0)
    BN1(r.y, v.y, 1)
    BN1(r.z, v.z, 2)
    BN1(r.w, v.w, 3)
#undef BN1
    ((float4*)out)[idx] = r;
}

extern "C" void kernel_launch(void* const* d_in, const int* in_sizes, int n_in,
                              void* d_out, int out_size, void* d_ws, size_t ws_size,
                              hipStream_t stream) {
    const float* x     = (const float*)d_in[0];
    const int*   ei    = (const int*)d_in[1];   // [2, E]: row = ei[e], col = ei[E+e]
    const float* ew    = (const float*)d_in[2];
    const float* W     = (const float*)d_in[3];
    const float* gamma = (const float*)d_in[4];
    const float* beta  = (const float*)d_in[5];

    const int n  = in_sizes[0] / C;
    const int nE = in_sizes[2];
    const int nb = (n + 255) / 256;
    const int SB = 256;  // k_stats blocks

    float* out = (float*)d_out;
    char* ws = (char*)d_ws;

    int2*   ev     = (int2*)ws;                               // E*8 B
    ushort* xb     = (ushort*)(ws + (size_t)nE * 8);          // n*C*2 B
    char*   p      = ws + (size_t)nE * 8 + (size_t)n * C * 2;
    u64*    packed = (u64*)p;              p += (size_t)n * 8;
    ushort* WbT    = (ushort*)p;           p += 128 * 128 * 2;
    float*  dis    = (float*)p;            p += (size_t)n * 4;
    int*    offs   = (int*)p;              p += (size_t)(n + 1) * 4;
    ushort* tkt    = (ushort*)p;           p += (size_t)nE * 2;
    int*    bsum   = (int*)p;              p += 512 * 4;
    float*  sums   = (float*)p;            p += 256 * 4;
    float*  part   = (float*)p;            p += (size_t)SB * 256 * 4;

    const long total4 = (long)n * 32;  // n*C/4

    hipMemsetAsync(packed, 0, (size_t)n * 8, stream);
    hipMemsetAsync(sums, 0, 256 * 4, stream);

    k_deg_hist<<<(nE + 2047) / 2048, 256, 0, stream>>>(ei + nE, ew, packed, tkt, nE);
    k_wcvt<<<64, 256, 0, stream>>>(W, WbT);
    k_scan1<<<nb, 256, 0, stream>>>(packed, dis, offs, bsum, n);
    k_scan2<<<1, 512, 0, stream>>>(bsum, nb);
    k_scan3<<<nb, 256, 0, stream>>>(offs, bsum, n, nE);
    k_cvt<<<(int)((total4 + 255) / 256), 256, 0, stream>>>((const float4*)x, dis, (ushort4*)xb, total4);
    k_build<<<(nE + 255) / 256, 256, 0, stream>>>(ei, ew, offs, tkt, ev, nE);
    k_segagg<<<(n + 15) / 16, 256, 0, stream>>>(xb, ev, offs, dis, out, n);
    k_gemm<<<(n + 63) / 64, 256, 0, stream>>>(out, WbT, n);
    k_stats<<<SB, 1024, 0, stream>>>((const float4*)out, part, n);
    k_finish<<<16, 256, 0, stream>>>(part, sums, SB);
    k_apply<<<(int)((total4 + 255) / 256), 256, 0, stream>>>(out, sums, gamma, beta, n);
}

// Round 9
// 234.386 us; speedup vs baseline: 7.1760x; 1.1783x over previous
//
#include <hip/hip_runtime.h>

#define C 128
#define MAXNB 1024
typedef unsigned int uint;
typedef unsigned short ushort;
typedef __attribute__((ext_vector_type(4))) float f32x4;
typedef __attribute__((ext_vector_type(8))) short bf16x8;

__device__ __forceinline__ float blo(uint u) { return __uint_as_float(u << 16); }
__device__ __forceinline__ float bhi(uint u) { return __uint_as_float(u & 0xFFFF0000u); }

// ---------------- A1: per-block bucket histogram (no global atomics) ----------------
__global__ __launch_bounds__(256) void k_hist(const int* __restrict__ col,
                                              int* __restrict__ counts,
                                              int nE, int NB, int NBLK) {
    __shared__ int hist[MAXNB];
    const int t = threadIdx.x, blk = blockIdx.x;
    for (int i = t; i < NB; i += 256) hist[i] = 0;
    __syncthreads();
    const int base = blk * 2048;
    for (int k = 0; k < 8; ++k) {
        int e = base + k * 256 + t;
        if (e < nE) atomicAdd(&hist[col[e] >> 7], 1);
    }
    __syncthreads();
    for (int i = t; i < NB; i += 256) counts[i * NBLK + blk] = hist[i];
}

// ---------------- exclusive scan of counts[scanN], 3 kernels ----------------
__global__ __launch_bounds__(256) void k_scan1(int* __restrict__ counts,
                                               int* __restrict__ bsum, int scanN) {
    __shared__ int s[256];
    int t = threadIdx.x;
    int i = blockIdx.x * 256 + t;
    int v = (i < scanN) ? counts[i] : 0;
    s[t] = v;
    __syncthreads();
    for (int d = 1; d < 256; d <<= 1) {
        int a = (t >= d) ? s[t - d] : 0;
        __syncthreads();
        s[t] += a;
        __syncthreads();
    }
    if (i < scanN) counts[i] = s[t] - v;
    if (t == 255) bsum[blockIdx.x] = s[255];
}

__global__ __launch_bounds__(256) void k_scan2(int* __restrict__ bsum, int nb) {
    __shared__ int s[256];
    __shared__ int carry;
    int t = threadIdx.x;
    if (t == 0) carry = 0;
    __syncthreads();
    int nch = (nb + 255) / 256;
    for (int c = 0; c < nch; ++c) {
        int i = c * 256 + t;
        int v = (i < nb) ? bsum[i] : 0;
        s[t] = v;
        __syncthreads();
        for (int d = 1; d < 256; d <<= 1) {
            int a = (t >= d) ? s[t - d] : 0;
            __syncthreads();
            s[t] += a;
            __syncthreads();
        }
        int cb = carry;
        if (i < nb) bsum[i] = s[t] - v + cb;
        int tot = s[255];
        __syncthreads();
        if (t == 0) carry = cb + tot;
        __syncthreads();
    }
}

__global__ __launch_bounds__(256) void k_scan3(int* __restrict__ counts,
                                               const int* __restrict__ bsum,
                                               int* __restrict__ bstart,
                                               int scanN, int NBLK, int NB, int nE) {
    int i = blockIdx.x * 256 + threadIdx.x;
    if (i >= scanN) return;
    int v = counts[i] + bsum[i >> 8];
    counts[i] = v;
    if (i % NBLK == 0) {
        bstart[i / NBLK] = v;
        if (i == 0) bstart[NB] = nE;
    }
}

// ---------------- A2: bin edges into bucket regions (no global atomics) ----------------
__global__ __launch_bounds__(256) void k_scatter(const int* __restrict__ ei,
                                                 const float* __restrict__ ew,
                                                 const int* __restrict__ counts,
                                                 int2* __restrict__ ev2,
                                                 int nE, int NB, int NBLK) {
    __shared__ int base_l[MAXNB];
    __shared__ int cnt_l[MAXNB];
    const int t = threadIdx.x, blk = blockIdx.x;
    for (int i = t; i < NB; i += 256) {
        base_l[i] = counts[i * NBLK + blk];
        cnt_l[i] = 0;
    }
    __syncthreads();
    const int base = blk * 2048;
    for (int k = 0; k < 8; ++k) {
        int e = base + k * 256 + t;
        if (e >= nE) continue;
        int c = ei[nE + e];
        int row = ei[e];
        int b = c >> 7;
        int pos = base_l[b] + atomicAdd(&cnt_l[b], 1);
        ev2[pos] = make_int2(((c & 127) << 25) | row, __float_as_int(ew[e]));
    }
}

// ---------------- B: per-bucket counting sort + degree (replaces deg_hist/build) ----------------
// Pass A: count per col + wsum per col (LDS). Scan -> per-col global bases.
// Writes offs[col], dis[col]. Pass B: re-read, LDS ticket, write col-sorted evs={row,w}.
__global__ __launch_bounds__(256) void k_sortdeg(const int2* __restrict__ ev2,
                                                 const int* __restrict__ bstart,
                                                 int2* __restrict__ evs,
                                                 int* __restrict__ offs,
                                                 float* __restrict__ dis,
                                                 int n, int nE) {
    __shared__ int cnt[128];
    __shared__ float wsum[128];
    __shared__ int cur[128];
    __shared__ int sc[128];
    const int t = threadIdx.x, b = blockIdx.x;
    if (t < 128) { cnt[t] = 0; wsum[t] = 0.f; }
    __syncthreads();
    const int s = bstart[b], e = bstart[b + 1];
    for (int i = s + t; i < e; i += 256) {
        int2 E = ev2[i];
        int cl = (uint)E.x >> 25;
        atomicAdd(&cnt[cl], 1);
        atomicAdd(&wsum[cl], __int_as_float(E.y));
    }
    __syncthreads();
    if (t < 128) sc[t] = cnt[t];
    __syncthreads();
    for (int d = 1; d < 128; d <<= 1) {
        int v = 0;
        if (t < 128 && t >= d) v = sc[t - d];
        __syncthreads();
        if (t < 128) sc[t] += v;
        __syncthreads();
    }
    if (t < 128) {
        int col = (b << 7) + t;
        int base = s + sc[t] - cnt[t];
        cur[t] = base;
        if (col < n) {
            offs[col] = base;
            dis[col] = rsqrtf(1.0f + wsum[t]);
        }
    }
    if (b == 0 && t == 0) offs[n] = nE;
    __syncthreads();
    for (int i = s + t; i < e; i += 256) {
        int2 E = ev2[i];
        int cl = (uint)E.x >> 25;
        int pos = atomicAdd(&cur[cl], 1);
        evs[pos] = make_int2(E.x & 0x1FFFFFF, E.y);
    }
}

// ---------------- xb' = bf16(dis[r] * x[r]) ----------------
__global__ __launch_bounds__(256) void k_cvt(const float4* __restrict__ x4,
                                             const float* __restrict__ dis,
                                             ushort4* __restrict__ xb4, long total4) {
    long i = (long)blockIdx.x * 256 + threadIdx.x;
    if (i >= total4) return;
    float d = dis[i >> 5];
    float4 v = x4[i];
    ushort4 r;
#define RNE(OUT, F)                                                     \
    {                                                                   \
        uint u = __float_as_uint((F) * d);                              \
        OUT = (ushort)((u + 0x7FFFu + ((u >> 16) & 1u)) >> 16);         \
    }
    RNE(r.x, v.x) RNE(r.y, v.y) RNE(r.z, v.z) RNE(r.w, v.w)
#undef RNE
    xb4[i] = r;
}

// ---------------- WbT[o][k] = bf16(W[k][o]) ----------------
__global__ __launch_bounds__(256) void k_wcvt(const float* __restrict__ W,
                                              ushort* __restrict__ WbT) {
    int idx = blockIdx.x * 256 + threadIdx.x;   // 16384 total
    int k = idx >> 7, o = idx & 127;
    uint u = __float_as_uint(W[idx]);
    WbT[o * 128 + k] = (ushort)((u + 0x7FFFu + ((u >> 16) & 1u)) >> 16);
}

// ---------------- segment aggregation ----------------
// out[col] = dis[col] * ( xb'[col] + sum_e w_e * xb'[row_e] )
__global__ __launch_bounds__(256) void k_segagg(const ushort* __restrict__ xb,
                                                const int2* __restrict__ ev,
                                                const int* __restrict__ offs,
                                                const float* __restrict__ dis,
                                                float* __restrict__ out, int n) {
    const int lane = threadIdx.x & 15;   // 0..15
    const int sub  = threadIdx.x >> 4;   // 0..15
    const int col  = blockIdx.x * 16 + sub;
    if (col >= n) return;

    uint4 sv = *(const uint4*)(xb + (size_t)col * C + lane * 8);
    float acc[8] = {blo(sv.x), bhi(sv.x), blo(sv.y), bhi(sv.y),
                    blo(sv.z), bhi(sv.z), blo(sv.w), bhi(sv.w)};

    int i = offs[col];
    const int end = offs[col + 1];

#define EDGE(E, V)                                                        \
    {                                                                     \
        float nw = __int_as_float(E.y);                                   \
        acc[0] = fmaf(nw, blo(V.x), acc[0]);                              \
        acc[1] = fmaf(nw, bhi(V.x), acc[1]);                              \
        acc[2] = fmaf(nw, blo(V.y), acc[2]);                              \
        acc[3] = fmaf(nw, bhi(V.y), acc[3]);                              \
        acc[4] = fmaf(nw, blo(V.z), acc[4]);                              \
        acc[5] = fmaf(nw, bhi(V.z), acc[5]);                              \
        acc[6] = fmaf(nw, blo(V.w), acc[6]);                              \
        acc[7] = fmaf(nw, bhi(V.w), acc[7]);                              \
    }

    for (; i + 4 <= end; i += 4) {
        int2 e0 = ev[i], e1 = ev[i + 1], e2 = ev[i + 2], e3 = ev[i + 3];
        uint4 v0 = *(const uint4*)(xb + (size_t)e0.x * C + lane * 8);
        uint4 v1 = *(const uint4*)(xb + (size_t)e1.x * C + lane * 8);
        uint4 v2 = *(const uint4*)(xb + (size_t)e2.x * C + lane * 8);
        uint4 v3 = *(const uint4*)(xb + (size_t)e3.x * C + lane * 8);
        EDGE(e0, v0)
        EDGE(e1, v1)
        EDGE(e2, v2)
        EDGE(e3, v3)
    }
    for (; i < end; ++i) {
        int2 e0 = ev[i];
        uint4 v0 = *(const uint4*)(xb + (size_t)e0.x * C + lane * 8);
        EDGE(e0, v0)
    }
#undef EDGE

    float d = dis[col];
    float4* orow = (float4*)(out + (size_t)col * C) + lane * 2;
    orow[0] = make_float4(d * acc[0], d * acc[1], d * acc[2], d * acc[3]);
    orow[1] = make_float4(d * acc[4], d * acc[5], d * acc[6], d * acc[7]);
}

// ---------------- MFMA GEMM: io = io @ W (in place), swapped operands ----------------
__global__ __launch_bounds__(256, 4) void k_gemm(float* __restrict__ io,
                                                 const ushort* __restrict__ WbT,
                                                 int n) {
    const int t = threadIdx.x;
    const int lane = t & 63;
    const int wv = t >> 6;
    const int lr = lane & 15;
    const int lk = lane >> 4;
    const long m = (long)blockIdx.x * 64 + wv * 16 + lr;
    const bool inr = m < (long)n;

    bf16x8 b[4];
#pragma unroll
    for (int s = 0; s < 4; ++s) {
        uint4 q0 = make_uint4(0, 0, 0, 0), q1 = q0;
        if (inr) {
            const uint4* p = (const uint4*)(io + (size_t)m * C + s * 32 + lk * 8);
            q0 = p[0];
            q1 = p[1];
        }
        union { uint u[4]; bf16x8 v; } cv;
        cv.u[0] = __builtin_amdgcn_perm(q0.y + 0x8000u, q0.x + 0x8000u, 0x07060302u);
        cv.u[1] = __builtin_amdgcn_perm(q0.w + 0x8000u, q0.z + 0x8000u, 0x07060302u);
        cv.u[2] = __builtin_amdgcn_perm(q1.y + 0x8000u, q1.x + 0x8000u, 0x07060302u);
        cv.u[3] = __builtin_amdgcn_perm(q1.w + 0x8000u, q1.z + 0x8000u, 0x07060302u);
        b[s] = cv.v;
    }

    f32x4 acc[8];
#pragma unroll
    for (int ot = 0; ot < 8; ++ot) acc[ot] = (f32x4){0.f, 0.f, 0.f, 0.f};

#pragma unroll 2
    for (int ot = 0; ot < 8; ++ot) {
        const ushort* wp = WbT + (ot * 16 + lr) * 128 + lk * 8;
        bf16x8 a0 = *(const bf16x8*)(wp);
        bf16x8 a1 = *(const bf16x8*)(wp + 32);
        bf16x8 a2 = *(const bf16x8*)(wp + 64);
        bf16x8 a3 = *(const bf16x8*)(wp + 96);
        acc[ot] = __builtin_amdgcn_mfma_f32_16x16x32_bf16(a0, b[0], acc[ot], 0, 0, 0);
        acc[ot] = __builtin_amdgcn_mfma_f32_16x16x32_bf16(a1, b[1], acc[ot], 0, 0, 0);
        acc[ot] = __builtin_amdgcn_mfma_f32_16x16x32_bf16(a2, b[2], acc[ot], 0, 0, 0);
        acc[ot] = __builtin_amdgcn_mfma_f32_16x16x32_bf16(a3, b[3], acc[ot], 0, 0, 0);
    }

    if (inr) {
        float* orow = io + (size_t)m * C + lk * 4;
#pragma unroll
        for (int ot = 0; ot < 8; ++ot)
            *(float4*)(orow + ot * 16) =
                make_float4(acc[ot][0], acc[ot][1], acc[ot][2], acc[ot][3]);
    }
}

// ---------------- BN stats: per-block partials (no global atomics) ----------------
__global__ __launch_bounds__(1024) void k_stats(const float4* __restrict__ o4,
                                                float* __restrict__ part, int n) {
    const int t = threadIdx.x;
    const int cg = t & 31;
    const int rl = t >> 5;
    float4 s = make_float4(0.f, 0.f, 0.f, 0.f);
    float4 q = s;
    for (int r = blockIdx.x * 32 + rl; r < n; r += gridDim.x * 32) {
        float4 v = o4[(size_t)r * 32 + cg];
        s.x += v.x; s.y += v.y; s.z += v.z; s.w += v.w;
        q.x = fmaf(v.x, v.x, q.x); q.y = fmaf(v.y, v.y, q.y);
        q.z = fmaf(v.z, v.z, q.z); q.w = fmaf(v.w, v.w, q.w);
    }
    __shared__ float4 ls[1024];
    __shared__ float4 lq[1024];
    ls[t] = s; lq[t] = q;
    __syncthreads();
    for (int d = 512; d >= 32; d >>= 1) {
        if (t < d) {
            float4 a = ls[t + d], bq = lq[t + d];
            ls[t].x += a.x; ls[t].y += a.y; ls[t].z += a.z; ls[t].w += a.w;
            lq[t].x += bq.x; lq[t].y += bq.y; lq[t].z += bq.z; lq[t].w += bq.w;
        }
        __syncthreads();
    }
    if (t < 32) {
        ((float4*)part)[blockIdx.x * 64 + t] = ls[t];
        ((float4*)part)[blockIdx.x * 64 + 32 + t] = lq[t];
    }
}

__global__ __launch_bounds__(256) void k_finish(const float* __restrict__ part,
                                                float* __restrict__ sums, int nblk) {
    int t = threadIdx.x;
    float s = 0.f;
    for (int b = blockIdx.x; b < nblk; b += gridDim.x) s += part[b * 256 + t];
    atomicAdd(&sums[t], s);
}

// ---------------- BN apply + ReLU (in place) ----------------
__global__ __launch_bounds__(256) void k_apply(float* __restrict__ out,
                                               const float* __restrict__ sums,
                                               const float* __restrict__ gamma,
                                               const float* __restrict__ beta,
                                               int n) {
    size_t idx = (size_t)blockIdx.x * 256 + threadIdx.x;
    size_t total = (size_t)n * 32;
    if (idx >= total) return;
    int cg = (int)(idx & 31);
    int c0 = cg * 4;
    float inv_n = 1.0f / (float)n;
    float4 v = ((const float4*)out)[idx];
    float4 r;
#define BN1(OUT, VIN, J)                                                   \
    {                                                                      \
        float mean = sums[c0 + J] * inv_n;                                 \
        float var  = fmaxf(sums[C + c0 + J] * inv_n - mean * mean, 0.f);   \
        float sc   = rsqrtf(var + 1e-5f) * gamma[c0 + J];                  \
        OUT = fmaxf(fmaf(VIN - mean, sc, beta[c0 + J]), 0.f);              \
    }
    BN1(r.x, v.x, 0)
    BN1(r.y, v.y, 1)
    BN1(r.z, v.z, 2)
    BN1(r.w, v.w, 3)
#undef BN1
    ((float4*)out)[idx] = r;
}

extern "C" void kernel_launch(void* const* d_in, const int* in_sizes, int n_in,
                              void* d_out, int out_size, void* d_ws, size_t ws_size,
                              hipStream_t stream) {
    const float* x     = (const float*)d_in[0];
    const int*   ei    = (const int*)d_in[1];   // [2, E]: row = ei[e], col = ei[E+e]
    const float* ew    = (const float*)d_in[2];
    const float* W     = (const float*)d_in[3];
    const float* gamma = (const float*)d_in[4];
    const float* beta  = (const float*)d_in[5];

    const int n  = in_sizes[0] / C;
    const int nE = in_sizes[2];

    const int NB    = (n + 127) >> 7;          // 128-col buckets
    const int NBLK  = (nE + 2047) / 2048;      // hist/scatter blocks
    const int scanN = NB * NBLK;
    const int scanB = (scanN + 255) / 256;
    const int SB    = 256;                     // k_stats blocks

    float* out = (float*)d_out;
    char* p = (char*)d_ws;
#define ALLOC(TYPE, NAME, BYTES) \
    TYPE NAME = (TYPE)p; p += ((size_t)(BYTES) + 255) & ~(size_t)255;
    ALLOC(int2*,   ev2,    (size_t)nE * 8)
    ALLOC(int2*,   evs,    (size_t)nE * 8)
    ALLOC(ushort*, xb,     (size_t)n * C * 2)
    ALLOC(int*,    counts, (size_t)scanN * 4)
    ALLOC(int*,    bsum,   (size_t)scanB * 4)
    ALLOC(int*,    bstart, (size_t)(NB + 1) * 4)
    ALLOC(float*,  dis,    (size_t)n * 4)
    ALLOC(int*,    offs,   (size_t)(n + 1) * 4)
    ALLOC(ushort*, WbT,    32768)
    ALLOC(float*,  sums,   1024)
    ALLOC(float*,  part,   (size_t)SB * 256 * 4)
#undef ALLOC

    const long total4 = (long)n * 32;  // n*C/4

    hipMemsetAsync(sums, 0, 256 * 4, stream);

    k_hist   <<<NBLK, 256, 0, stream>>>(ei + nE, counts, nE, NB, NBLK);
    k_scan1  <<<scanB, 256, 0, stream>>>(counts, bsum, scanN);
    k_scan2  <<<1, 256, 0, stream>>>(bsum, scanB);
    k_scan3  <<<scanB, 256, 0, stream>>>(counts, bsum, bstart, scanN, NBLK, NB, nE);
    k_scatter<<<NBLK, 256, 0, stream>>>(ei, ew, counts, ev2, nE, NB, NBLK);
    k_sortdeg<<<NB, 256, 0, stream>>>(ev2, bstart, evs, offs, dis, n, nE);
    k_wcvt   <<<64, 256, 0, stream>>>(W, WbT);
    k_cvt    <<<(int)((total4 + 255) / 256), 256, 0, stream>>>((const float4*)x, dis, (ushort4*)xb, total4);
    k_segagg <<<(n + 15) / 16, 256, 0, stream>>>(xb, evs, offs, dis, out, n);
    k_gemm   <<<(n + 63) / 64, 256, 0, stream>>>(out, WbT, n);
    k_stats  <<<SB, 1024, 0, stream>>>((const float4*)out, part, n);
    k_finish <<<16, 256, 0, stream>>>(part, sums, SB);
    k_apply  <<<(int)((total4 + 255) / 256), 256, 0, stream>>>(out, sums, gamma, beta, n);
}